// Round 24
// baseline (105.122 us; speedup 1.0000x reference)
//
#include <hip/hip_runtime.h>

#define HW 512
#define NSTATE (HW * HW)   // 262144
#define NC4_X 196608       // x as float4 (3*H*W/4)
#define NC4_POLROW 262144  // Wpol row stride in float4 (4 MiB)
#define NC4_V 65536        // v as float4

#define CH4 1024   // float4 per wave-chunk (16 KB)
#define NCH_X 192  // chunks per W1 row

// ws layout (float offsets)
#define WS_PART1 0       // 6144
#define WS_PARTP 6144    // 8192
#define WS_H2 14336      // 64
#define WS_DRO 16384     // 262144
#define WS_DRI 278528    // 262144
#define WS_DP 540672     // 262144
#define WS_V 802816      // 262144

#define SGB __builtin_amdgcn_sched_group_barrier

typedef float f4v __attribute__((ext_vector_type(4)));

__device__ __forceinline__ float wred(float a) {
  a += __shfl_xor(a, 32);
  a += __shfl_xor(a, 16);
  a += __shfl_xor(a, 8);
  a += __shfl_xor(a, 4);
  a += __shfl_xor(a, 2);
  a += __shfl_xor(a, 1);
  return a;
}

__device__ __forceinline__ float span_dot(const float4* __restrict__ wp,
                                          const float4* __restrict__ xp) {
  float acc = 0.f;
#pragma unroll
  for (int bt = 0; bt < 2; ++bt) {
    float4 w[8], xv[8];
#pragma unroll
    for (int j = 0; j < 8; ++j) w[j] = wp[bt * 512 + j * 64];
#pragma unroll
    for (int j = 0; j < 8; ++j) xv[j] = xp[bt * 512 + j * 64];
    SGB(0x020, 16, 0);
#pragma unroll
    for (int j = 0; j < 8; ++j)
      acc += w[j].x * xv[j].x + w[j].y * xv[j].y + w[j].z * xv[j].z +
             w[j].w * xv[j].w;
  }
  return acc;
}

// ---------------------------------------------------------------------------
// K1: W1@x partials, flat-linear span_dot. 1536 blocks. (L3-resident.)
// ---------------------------------------------------------------------------
__global__ __launch_bounds__(256) void mv_w1(const float4* __restrict__ W1,
                                             const float4* __restrict__ x,
                                             float* __restrict__ part1) {
  int b = blockIdx.x;
  int row = b / 48, cb = b - row * 48;
  int tid = threadIdx.x, wave = tid >> 6, lane = tid & 63;
  int ch = cb * 4 + wave;
  const float4* __restrict__ wp =
      W1 + (size_t)row * NC4_X + (size_t)ch * CH4 + lane;
  const float4* __restrict__ xp = x + (size_t)ch * CH4 + lane;
  float acc = span_dot(wp, xp);
  acc = wred(acc);
  if (lane == 0) part1[ch * 32 + row] = acc;
}

// ---------------------------------------------------------------------------
// K2: finish_h (1 block).
// ---------------------------------------------------------------------------
__global__ __launch_bounds__(1024) void finish_h(
    const float* __restrict__ partials, const float* __restrict__ b1,
    const float* __restrict__ W2, const float* __restrict__ b2,
    float* __restrict__ h2out) {
  __shared__ float red[32][32];
  __shared__ float h1[32];
  int tid = threadIdx.x;
  int row = tid & 31, grp = tid >> 5;
  float s = 0.f;
  for (int b = grp; b < NCH_X; b += 32) s += partials[b * 32 + row];
  red[grp][row] = s;
  __syncthreads();
  if (tid < 32) {
    float t = b1[tid];
    for (int g = 0; g < 32; ++g) t += red[g][tid];
    h1[tid] = fmaxf(t, 0.f);
  }
  __syncthreads();
  if (tid < 64) {
    float t = b2[tid];
    for (int k = 0; k < 32; ++k) t += W2[tid * 32 + k] * h1[k];
    h2out[tid] = fmaxf(t, 0.f);
  }
}

// ---------------------------------------------------------------------------
// K3: rop_part, PIPELINED (R24). R23 proved 16 KB/wave in flight one-shot is
// NOT enough cold — the drain (vmcnt(0)) + consume + wave-exit leaves the
// pipe idle every burst. New: each wave does 3 chunks (rows gw*64..+63 of
// Wro, Wri, Wp) with issue/wait decoupled: issue A, issue B, vmcnt(16)->
// consume A, issue A', vmcnt(16)->consume B, vmcnt(0)->consume A'. Always
// >=16 KB in flight while computing; no __syncthreads in the pipeline (its
// implicit vmcnt(0) would drain it) — dots bounce is wave-internal, fenced
// by lgkmcnt(0)+sched_barrier. nt loads kept. 1024 blocks.
// ---------------------------------------------------------------------------
__device__ __forceinline__ void issue16(const float4* __restrict__ wp,
                                        f4v* w) {
  const float* a0 = (const float*)(wp);
  const float* a1 = (const float*)(wp + 256);
  const float* a2 = (const float*)(wp + 512);
  const float* a3 = (const float*)(wp + 768);
  asm volatile(
      "global_load_dwordx4 %0, %16, off nt\n\t"
      "global_load_dwordx4 %1, %16, off offset:1024 nt\n\t"
      "global_load_dwordx4 %2, %16, off offset:2048 nt\n\t"
      "global_load_dwordx4 %3, %16, off offset:3072 nt\n\t"
      "global_load_dwordx4 %4, %17, off nt\n\t"
      "global_load_dwordx4 %5, %17, off offset:1024 nt\n\t"
      "global_load_dwordx4 %6, %17, off offset:2048 nt\n\t"
      "global_load_dwordx4 %7, %17, off offset:3072 nt\n\t"
      "global_load_dwordx4 %8, %18, off nt\n\t"
      "global_load_dwordx4 %9, %18, off offset:1024 nt\n\t"
      "global_load_dwordx4 %10, %18, off offset:2048 nt\n\t"
      "global_load_dwordx4 %11, %18, off offset:3072 nt\n\t"
      "global_load_dwordx4 %12, %19, off nt\n\t"
      "global_load_dwordx4 %13, %19, off offset:1024 nt\n\t"
      "global_load_dwordx4 %14, %19, off offset:2048 nt\n\t"
      "global_load_dwordx4 %15, %19, off offset:3072 nt"
      : "=&v"(w[0]), "=&v"(w[1]), "=&v"(w[2]), "=&v"(w[3]), "=&v"(w[4]),
        "=&v"(w[5]), "=&v"(w[6]), "=&v"(w[7]), "=&v"(w[8]), "=&v"(w[9]),
        "=&v"(w[10]), "=&v"(w[11]), "=&v"(w[12]), "=&v"(w[13]), "=&v"(w[14]),
        "=&v"(w[15])
      : "v"(a0), "v"(a1), "v"(a2), "v"(a3)
      : "memory");
}

__device__ __forceinline__ void consume16(const f4v* w, float4 h4, int wave,
                                          int lane, float (*dots)[64],
                                          float* __restrict__ Dst) {
  float part[16];
#pragma unroll
  for (int j = 0; j < 16; ++j)
    part[j] = w[j][0] * h4.x + w[j][1] * h4.y + w[j][2] * h4.z + w[j][3] * h4.w;
#pragma unroll
  for (int j = 0; j < 16; ++j) {
    part[j] += __shfl_xor(part[j], 8);
    part[j] += __shfl_xor(part[j], 4);
    part[j] += __shfl_xor(part[j], 2);
    part[j] += __shfl_xor(part[j], 1);
  }
  int k = lane & 15, grp = lane >> 4;
  if (k == 0) {
#pragma unroll
    for (int j = 0; j < 16; ++j) dots[wave][j * 4 + grp] = part[j];
  }
  asm volatile("s_waitcnt lgkmcnt(0)" ::: "memory");
  __builtin_amdgcn_sched_barrier(0);
  Dst[lane] = dots[wave][lane];  // wave-internal exchange; coalesced store
}

#define VMW16 do { asm volatile("s_waitcnt vmcnt(16)" ::: "memory"); \
                   __builtin_amdgcn_sched_barrier(0); } while (0)
#define VMW0 do { asm volatile("s_waitcnt vmcnt(0)" ::: "memory"); \
                  __builtin_amdgcn_sched_barrier(0); } while (0)

__global__ __launch_bounds__(256, 2) void rop_part(
    const float4* __restrict__ Wro4, const float4* __restrict__ Wri4,
    const float4* __restrict__ Wp4, const float* __restrict__ h2,
    float* __restrict__ dro, float* __restrict__ dri,
    float* __restrict__ dp) {
  __shared__ float dots[4][64];
  int tid = threadIdx.x, wave = tid >> 6, lane = tid & 63;
  int gw = blockIdx.x * 4 + wave;  // [0,4096): 64-row group
  float4 h4 = ((const float4*)h2)[lane & 15];
  const float4* __restrict__ p0 = Wro4 + (size_t)gw * CH4 + lane;
  const float4* __restrict__ p1 = Wri4 + (size_t)gw * CH4 + lane;
  const float4* __restrict__ p2 = Wp4 + (size_t)gw * CH4 + lane;
  f4v A[16], B[16];
  issue16(p0, A);
  issue16(p1, B);
  VMW16;  // A ready, B (16 ops) in flight
  consume16(A, h4, wave, lane, dots, dro + (size_t)gw * 64);
  issue16(p2, A);
  VMW16;  // B ready (+store drained), A' in flight
  consume16(B, h4, wave, lane, dots, dri + (size_t)gw * 64);
  VMW0;  // tail drain
  consume16(A, h4, wave, lane, dots, dp + (size_t)gw * 64);
}

// ---------------------------------------------------------------------------
// K4: valiter (R17 structure) + sigmoid/bias/combine in the load stage.
// ---------------------------------------------------------------------------
#define VTILE 16
#define VHALO 10
#define ULW 44
#define ULH 38
__device__ __forceinline__ void row_win(const float* __restrict__ r,
                                        float e[6]) {
  float4 L = *reinterpret_cast<const float4*>(r - 4);
  float4 M = *reinterpret_cast<const float4*>(r);
  float4 R = *reinterpret_cast<const float4*>(r + 4);
  e[0] = L.w; e[1] = M.x; e[2] = M.y; e[3] = M.z; e[4] = M.w; e[5] = R.x;
}
__global__ __launch_bounds__(384) void valiter_kernel(
    const float* __restrict__ dro, const float* __restrict__ dri,
    const float* __restrict__ dp, const float* __restrict__ bro,
    const float* __restrict__ bri, const float* __restrict__ bp,
    float* __restrict__ vout) {
  __shared__ float ua[ULH * ULW];
  __shared__ float ub[ULH * ULW];
  int tid = threadIdx.x;
  int blk = blockIdx.x;
  int ti = blk >> 5, tj = blk & 31;
  for (int idx = tid; idx < ULH * ULW; idx += 384) {
    ua[idx] = 0.f;
    ub[idx] = 0.f;
  }
  int i = tid / 9, j4 = tid - i * 9;
  bool active = (i < 36);
  int cb = 4 + 4 * j4;
  float pp[4], rr[4];
  if (active) {
    int gi = ti * VTILE - VHALO + i;
    int gj0 = tj * VTILE - VHALO + 4 * j4;
#pragma unroll
    for (int k = 0; k < 4; ++k) {
      int gj = gj0 + k;
      bool ok = (gi >= 0) & (gi < HW) & (gj >= 0) & (gj < HW);
      if (ok) {
        int g = gi * HW + gj;
        float sro = 1.f / (1.f + __expf(-(dro[g] + bro[g])));
        float sri = 1.f / (1.f + __expf(-(dri[g] + bri[g])));
        pp[k] = 1.f / (1.f + __expf(-(dp[g] + bp[g])));
        rr[k] = sri - sro;
      } else {
        pp[k] = 0.f;
        rr[k] = 0.f;
      }
    }
  }
  __syncthreads();
  if (active) {
    *reinterpret_cast<float4*>(&ua[(i + 1) * ULW + cb]) =
        make_float4(rr[0], rr[1], rr[2], rr[3]);
  }
  __syncthreads();
  float* src = ua;
  float* dst = ub;
  for (int q = 0; q < 9; ++q) {
    int lo = q + 1, hi = 35 - q;
    if (active && i >= lo && i < hi && (4 * j4 + 4) > lo && (4 * j4) < hi) {
      float eA[6], eB[6], eC[6];
      row_win(src + i * ULW + cb, eA);
      row_win(src + (i + 1) * ULW + cb, eB);
      row_win(src + (i + 2) * ULW + cb, eC);
      float res[4];
#pragma unroll
      for (int k = 0; k < 4; ++k) {
        float a = fmaxf(fmaxf(eA[k], eA[k + 1]), eA[k + 2]);
        float c = fmaxf(fmaxf(eC[k], eC[k + 1]), eC[k + 2]);
        float b = fmaxf(eB[k], eB[k + 2]);
        float m = fmaxf(fmaxf(a, c), b);
        res[k] = m * pp[k] + rr[k];
      }
      *reinterpret_cast<float4*>(&dst[(i + 1) * ULW + cb]) =
          make_float4(res[0], res[1], res[2], res[3]);
    }
    __syncthreads();
    float* t_ = src;
    src = dst;
    dst = t_;
  }
  if (active && i >= 10 && i < 26 && (4 * j4 + 4) > 10 && (4 * j4) < 26) {
    float eA[6], eB[6], eC[6];
    row_win(src + i * ULW + cb, eA);
    row_win(src + (i + 1) * ULW + cb, eB);
    row_win(src + (i + 2) * ULW + cb, eC);
#pragma unroll
    for (int k = 0; k < 4; ++k) {
      int cj = 4 * j4 + k;
      if (cj >= 10 && cj < 26) {
        float a = fmaxf(fmaxf(eA[k], eA[k + 1]), eA[k + 2]);
        float c = fmaxf(fmaxf(eC[k], eC[k + 1]), eC[k + 2]);
        float b = fmaxf(eB[k], eB[k + 2]);
        float m = fmaxf(fmaxf(a, c), b);
        vout[(ti * VTILE + i - 10) * HW + tj * VTILE + cj - 10] = m;
      }
    }
  }
}

// ---------------------------------------------------------------------------
// K5: all Wpol in one flat span_dot sweep. 2048 blocks. (L3-resident.)
// ---------------------------------------------------------------------------
__global__ __launch_bounds__(256) void mv_pol(const float4* __restrict__ Wpol,
                                              const float4* __restrict__ x,
                                              const float4* __restrict__ v,
                                              float* __restrict__ partP) {
  int b = blockIdx.x;
  int tid = threadIdx.x, wave = tid >> 6, lane = tid & 63;
  int f = b * 4 + wave;
  int row = f >> 8, rc = f & 255;
  const float4* __restrict__ wp = Wpol + (size_t)f * CH4 + lane;
  const float4* __restrict__ xp =
      (rc < 64) ? (v + (size_t)rc * CH4 + lane)
                : (x + (size_t)(rc - 64) * CH4 + lane);
  float acc = span_dot(wp, xp);
  acc = wred(acc);
  if (lane == 0) partP[rc * 32 + row] = acc;
}

// ---------------------------------------------------------------------------
// K6: finish_pol (1 block).
// ---------------------------------------------------------------------------
__global__ __launch_bounds__(1024) void finish_pol(
    const float* __restrict__ partP, const float* __restrict__ bpol,
    const float* __restrict__ Whead, const float* __restrict__ bhead,
    const float* __restrict__ v, const int* __restrict__ pos,
    float* __restrict__ out) {
  __shared__ float red[32][32];
  __shared__ float hp[32];
  __shared__ float logits[8];
  int tid = threadIdx.x;
  int row = tid & 31, grp = tid >> 5;
  float s = 0.f;
  for (int b = grp; b < 256; b += 32) s += partP[b * 32 + row];
  red[grp][row] = s;
  __syncthreads();
  if (tid < 32) {
    float t = bpol[tid];
    for (int g = 0; g < 32; ++g) t += red[g][tid];
    hp[tid] = fmaxf(t, 0.f);
  }
  __syncthreads();
  if (tid < 8) {
    float t = bhead[tid];
    for (int k = 0; k < 32; ++k) t += Whead[tid * 32 + k] * hp[k];
    logits[tid] = t;
  }
  __syncthreads();
  if (tid == 0) {
    float mx = logits[0];
    for (int j = 1; j < 8; ++j) mx = fmaxf(mx, logits[j]);
    float e[8], sum = 0.f;
    for (int j = 0; j < 8; ++j) {
      e[j] = __expf(logits[j] - mx);
      sum += e[j];
    }
    for (int j = 0; j < 8; ++j) out[j] = e[j] / sum;
    out[8] = v[pos[0] * HW + pos[1]];
  }
}

extern "C" void kernel_launch(void* const* d_in, const int* in_sizes, int n_in,
                              void* d_out, int out_size, void* d_ws,
                              size_t ws_size, hipStream_t stream) {
  const float* x = (const float*)d_in[0];
  const int* pos = (const int*)d_in[1];
  const float* W1 = (const float*)d_in[2];
  const float* b1 = (const float*)d_in[3];
  const float* W2 = (const float*)d_in[4];
  const float* b2 = (const float*)d_in[5];
  const float* Wro = (const float*)d_in[6];
  const float* bro = (const float*)d_in[7];
  const float* Wri = (const float*)d_in[8];
  const float* bri = (const float*)d_in[9];
  const float* Wp = (const float*)d_in[10];
  const float* bp = (const float*)d_in[11];
  const float* Wpol = (const float*)d_in[12];
  const float* bpol = (const float*)d_in[13];
  const float* Whead = (const float*)d_in[14];
  const float* bhead = (const float*)d_in[15];
  float* ws = (float*)d_ws;
  float* out = (float*)d_out;

  float* part1 = ws + WS_PART1;
  float* partP = ws + WS_PARTP;
  float* h2 = ws + WS_H2;
  float* drob = ws + WS_DRO;
  float* drib = ws + WS_DRI;
  float* dpb = ws + WS_DP;
  float* vbuf = ws + WS_V;

  // K1: W1@x partials
  mv_w1<<<1536, 256, 0, stream>>>((const float4*)W1, (const float4*)x, part1);
  // K2: h1 -> h2
  finish_h<<<1, 1024, 0, stream>>>(part1, b1, W2, b2, h2);
  // K3: raw dots for Wro/Wri/Wp — pipelined nt stream
  rop_part<<<1024, 256, 0, stream>>>((const float4*)Wro, (const float4*)Wri,
                                     (const float4*)Wp, h2, drob, drib, dpb);
  // K4: sigmoid/combine + 10 value-iteration steps
  valiter_kernel<<<1024, 384, 0, stream>>>(drob, drib, dpb, bro, bri, bp,
                                           vbuf);
  // K5: all Wpol partials
  mv_pol<<<2048, 256, 0, stream>>>((const float4*)Wpol, (const float4*)x,
                                   (const float4*)vbuf, partP);
  // K6: heads + softmax + state value
  finish_pol<<<1, 1024, 0, stream>>>(partP, bpol, Whead, bhead, vbuf, pos,
                                     out);
}

// Round 25
// 100.910 us; speedup vs baseline: 1.0417x; 1.0417x over previous
//
#include <hip/hip_runtime.h>

#define HW 512
#define NSTATE (HW * HW)   // 262144
#define NC4_X 196608       // x as float4 (3*H*W/4)
#define NC4_POLROW 262144  // Wpol row stride in float4 (4 MiB)
#define NC4_V 65536        // v as float4

#define CH4 1024   // float4 per wave-chunk (16 KB)
#define NCH_X 192  // chunks per W1 row
#define NCH_V 64   // chunks per WpolV row

// ws layout (float offsets)
#define WS_PART1 0      // 6144
#define WS_PARTP 6144   // 8192 (rows 0..63 = v-part, 64..255 = x-part)
#define WS_H2 14336     // 64
#define WS_P 14400      // 262144
#define WS_RD (WS_P + NSTATE)
#define WS_V (WS_RD + NSTATE)

#define SGB __builtin_amdgcn_sched_group_barrier

typedef float f4v __attribute__((ext_vector_type(4)));

__device__ __forceinline__ float wred(float a) {
  a += __shfl_xor(a, 32);
  a += __shfl_xor(a, 16);
  a += __shfl_xor(a, 8);
  a += __shfl_xor(a, 4);
  a += __shfl_xor(a, 2);
  a += __shfl_xor(a, 1);
  return a;
}

__device__ __forceinline__ float span_dot(const float4* __restrict__ wp,
                                          const float4* __restrict__ xp) {
  float acc = 0.f;
#pragma unroll
  for (int bt = 0; bt < 2; ++bt) {
    float4 w[8], xv[8];
#pragma unroll
    for (int j = 0; j < 8; ++j) w[j] = wp[bt * 512 + j * 64];
#pragma unroll
    for (int j = 0; j < 8; ++j) xv[j] = xp[bt * 512 + j * 64];
    SGB(0x020, 16, 0);
#pragma unroll
    for (int j = 0; j < 8; ++j)
      acc += w[j].x * xv[j].x + w[j].y * xv[j].y + w[j].z * xv[j].z +
             w[j].w * xv[j].w;
  }
  return acc;
}

// ---------------------------------------------------------------------------
// K1: W1@x partials, flat-linear span_dot. 1536 blocks. (L3-resident.)
// ---------------------------------------------------------------------------
__global__ __launch_bounds__(256) void mv_w1(const float4* __restrict__ W1,
                                             const float4* __restrict__ x,
                                             float* __restrict__ part1) {
  int b = blockIdx.x;
  int row = b / 48, cb = b - row * 48;
  int tid = threadIdx.x, wave = tid >> 6, lane = tid & 63;
  int ch = cb * 4 + wave;
  const float4* __restrict__ wp =
      W1 + (size_t)row * NC4_X + (size_t)ch * CH4 + lane;
  const float4* __restrict__ xp = x + (size_t)ch * CH4 + lane;
  float acc = span_dot(wp, xp);
  acc = wred(acc);
  if (lane == 0) part1[ch * 32 + row] = acc;
}

// ---------------------------------------------------------------------------
// K2: finish_h (1 block).
// ---------------------------------------------------------------------------
__global__ __launch_bounds__(1024) void finish_h(
    const float* __restrict__ partials, const float* __restrict__ b1,
    const float* __restrict__ W2, const float* __restrict__ b2,
    float* __restrict__ h2out) {
  __shared__ float red[32][32];
  __shared__ float h1[32];
  int tid = threadIdx.x;
  int row = tid & 31, grp = tid >> 5;
  float s = 0.f;
  for (int b = grp; b < NCH_X; b += 32) s += partials[b * 32 + row];
  red[grp][row] = s;
  __syncthreads();
  if (tid < 32) {
    float t = b1[tid];
    for (int g = 0; g < 32; ++g) t += red[g][tid];
    h1[tid] = fmaxf(t, 0.f);
  }
  __syncthreads();
  if (tid < 64) {
    float t = b2[tid];
    for (int k = 0; k < 32; ++k) t += W2[tid * 32 + k] * h1[k];
    h2out[tid] = fmaxf(t, 0.f);
  }
}

// ---------------------------------------------------------------------------
// K3: ropx (R25). Heterogeneous co-dispatch, interleaved 2:3 —
//  rop blocks (1024): R24's pipelined nt stream over Wro/Wri/Wp rows
//    gw*64..+63; all three dot-sets land in LDS, then the wave computes
//    bias+sigmoid+combine IN rop's idle VALU and stores p/rd directly.
//  polx blocks (1536): Wpol x-column partials (L3-resident bytes — uses
//    fabric BW that rop's HBM stream leaves idle; true overlap).
// R24 proved wave-depth fixes null — this attacks the serial chain instead.
// ---------------------------------------------------------------------------
__device__ __forceinline__ void issue16(const float4* __restrict__ wp,
                                        f4v* w) {
  const float* a0 = (const float*)(wp);
  const float* a1 = (const float*)(wp + 256);
  const float* a2 = (const float*)(wp + 512);
  const float* a3 = (const float*)(wp + 768);
  asm volatile(
      "global_load_dwordx4 %0, %16, off nt\n\t"
      "global_load_dwordx4 %1, %16, off offset:1024 nt\n\t"
      "global_load_dwordx4 %2, %16, off offset:2048 nt\n\t"
      "global_load_dwordx4 %3, %16, off offset:3072 nt\n\t"
      "global_load_dwordx4 %4, %17, off nt\n\t"
      "global_load_dwordx4 %5, %17, off offset:1024 nt\n\t"
      "global_load_dwordx4 %6, %17, off offset:2048 nt\n\t"
      "global_load_dwordx4 %7, %17, off offset:3072 nt\n\t"
      "global_load_dwordx4 %8, %18, off nt\n\t"
      "global_load_dwordx4 %9, %18, off offset:1024 nt\n\t"
      "global_load_dwordx4 %10, %18, off offset:2048 nt\n\t"
      "global_load_dwordx4 %11, %18, off offset:3072 nt\n\t"
      "global_load_dwordx4 %12, %19, off nt\n\t"
      "global_load_dwordx4 %13, %19, off offset:1024 nt\n\t"
      "global_load_dwordx4 %14, %19, off offset:2048 nt\n\t"
      "global_load_dwordx4 %15, %19, off offset:3072 nt"
      : "=&v"(w[0]), "=&v"(w[1]), "=&v"(w[2]), "=&v"(w[3]), "=&v"(w[4]),
        "=&v"(w[5]), "=&v"(w[6]), "=&v"(w[7]), "=&v"(w[8]), "=&v"(w[9]),
        "=&v"(w[10]), "=&v"(w[11]), "=&v"(w[12]), "=&v"(w[13]), "=&v"(w[14]),
        "=&v"(w[15])
      : "v"(a0), "v"(a1), "v"(a2), "v"(a3)
      : "memory");
}

__device__ __forceinline__ void consume16(const f4v* w, float4 h4, int wave,
                                          int m, int lane,
                                          float (*dots)[3][64]) {
  float part[16];
#pragma unroll
  for (int j = 0; j < 16; ++j)
    part[j] = w[j][0] * h4.x + w[j][1] * h4.y + w[j][2] * h4.z + w[j][3] * h4.w;
#pragma unroll
  for (int j = 0; j < 16; ++j) {
    part[j] += __shfl_xor(part[j], 8);
    part[j] += __shfl_xor(part[j], 4);
    part[j] += __shfl_xor(part[j], 2);
    part[j] += __shfl_xor(part[j], 1);
  }
  int k = lane & 15, grp = lane >> 4;
  if (k == 0) {
#pragma unroll
    for (int j = 0; j < 16; ++j) dots[wave][m][j * 4 + grp] = part[j];
  }
}

#define VMW16 do { asm volatile("s_waitcnt vmcnt(16)" ::: "memory"); \
                   __builtin_amdgcn_sched_barrier(0); } while (0)
#define VMW0 do { asm volatile("s_waitcnt vmcnt(0)" ::: "memory"); \
                  __builtin_amdgcn_sched_barrier(0); } while (0)

__global__ __launch_bounds__(256, 2) void ropx(
    const float4* __restrict__ Wro4, const float4* __restrict__ Wri4,
    const float4* __restrict__ Wp4, const float* __restrict__ h2,
    const float* __restrict__ bro, const float* __restrict__ bri,
    const float* __restrict__ bp, float* __restrict__ p_out,
    float* __restrict__ rd_out, const float4* __restrict__ Wpol,
    const float4* __restrict__ x, float* __restrict__ partP) {
  __shared__ float dots[4][3][64];
  int tid = threadIdx.x, wave = tid >> 6, lane = tid & 63;
  int b5 = blockIdx.x / 5, m5 = blockIdx.x - b5 * 5;
  if (m5 >= 2) {  // ---- polx path (1536 blocks, L3-resident) ----
    int xblk = b5 * 3 + (m5 - 2);  // [0,1536)
    int row = xblk / 48, cb = xblk - row * 48;
    int ch = cb * 4 + wave;  // x-chunk 0..191
    const float4* __restrict__ wp =
        Wpol + (size_t)row * NC4_POLROW + NC4_V + (size_t)ch * CH4 + lane;
    const float4* __restrict__ xp = x + (size_t)ch * CH4 + lane;
    float acc = span_dot(wp, xp);
    acc = wred(acc);
    if (lane == 0) partP[(64 + ch) * 32 + row] = acc;
    return;
  }
  // ---- rop path (1024 blocks, pipelined nt HBM stream) ----
  int rblk = b5 * 2 + m5;          // [0,1024)
  int gw = rblk * 4 + wave;        // [0,4096): 64-row group
  float4 h4 = ((const float4*)h2)[lane & 15];
  const float4* __restrict__ p0 = Wro4 + (size_t)gw * CH4 + lane;
  const float4* __restrict__ p1 = Wri4 + (size_t)gw * CH4 + lane;
  const float4* __restrict__ p2 = Wp4 + (size_t)gw * CH4 + lane;
  f4v A[16], B[16];
  issue16(p0, A);
  issue16(p1, B);
  VMW16;  // A ready, B in flight
  consume16(A, h4, wave, 0, lane, dots);
  issue16(p2, A);
  VMW16;  // B ready, A' in flight
  consume16(B, h4, wave, 1, lane, dots);
  VMW0;  // tail drain
  consume16(A, h4, wave, 2, lane, dots);
  asm volatile("s_waitcnt lgkmcnt(0)" ::: "memory");
  __builtin_amdgcn_sched_barrier(0);
  // epilogue: bias + sigmoid + combine in rop's idle VALU; coalesced stores
  int o = gw * 64 + lane;
  float dro = dots[wave][0][lane] + bro[o];
  float dri = dots[wave][1][lane] + bri[o];
  float dp = dots[wave][2][lane] + bp[o];
  float sro = 1.f / (1.f + __expf(-dro));
  float sri = 1.f / (1.f + __expf(-dri));
  float pv = 1.f / (1.f + __expf(-dp));
  p_out[o] = pv;
  rd_out[o] = sri - sro;
}

// ---------------------------------------------------------------------------
// K4: valiter (R17 form, measured ~9 µs: one barrier/iter, float4 LDS,
// p/rd in registers, shrinking active region). 1024 blocks x 384 threads.
// ---------------------------------------------------------------------------
#define VTILE 16
#define VHALO 10
#define ULW 44
#define ULH 38
__device__ __forceinline__ void row_win(const float* __restrict__ r,
                                        float e[6]) {
  float4 L = *reinterpret_cast<const float4*>(r - 4);
  float4 M = *reinterpret_cast<const float4*>(r);
  float4 R = *reinterpret_cast<const float4*>(r + 4);
  e[0] = L.w; e[1] = M.x; e[2] = M.y; e[3] = M.z; e[4] = M.w; e[5] = R.x;
}
__global__ __launch_bounds__(384) void valiter_kernel(
    const float* __restrict__ p, const float* __restrict__ rd,
    float* __restrict__ vout) {
  __shared__ float ua[ULH * ULW];
  __shared__ float ub[ULH * ULW];
  int tid = threadIdx.x;
  int blk = blockIdx.x;
  int ti = blk >> 5, tj = blk & 31;
  for (int idx = tid; idx < ULH * ULW; idx += 384) {
    ua[idx] = 0.f;
    ub[idx] = 0.f;
  }
  int i = tid / 9, j4 = tid - i * 9;
  bool active = (i < 36);
  int cb = 4 + 4 * j4;
  float pp[4], rr[4];
  if (active) {
    int gi = ti * VTILE - VHALO + i;
    int gj0 = tj * VTILE - VHALO + 4 * j4;
#pragma unroll
    for (int k = 0; k < 4; ++k) {
      int gj = gj0 + k;
      bool ok = (gi >= 0) & (gi < HW) & (gj >= 0) & (gj < HW);
      int gidx = gi * HW + gj;
      pp[k] = ok ? p[gidx] : 0.f;
      rr[k] = ok ? rd[gidx] : 0.f;
    }
  }
  __syncthreads();
  if (active) {
    *reinterpret_cast<float4*>(&ua[(i + 1) * ULW + cb]) =
        make_float4(rr[0], rr[1], rr[2], rr[3]);
  }
  __syncthreads();
  float* src = ua;
  float* dst = ub;
  for (int q = 0; q < 9; ++q) {
    int lo = q + 1, hi = 35 - q;
    if (active && i >= lo && i < hi && (4 * j4 + 4) > lo && (4 * j4) < hi) {
      float eA[6], eB[6], eC[6];
      row_win(src + i * ULW + cb, eA);
      row_win(src + (i + 1) * ULW + cb, eB);
      row_win(src + (i + 2) * ULW + cb, eC);
      float res[4];
#pragma unroll
      for (int k = 0; k < 4; ++k) {
        float a = fmaxf(fmaxf(eA[k], eA[k + 1]), eA[k + 2]);
        float c = fmaxf(fmaxf(eC[k], eC[k + 1]), eC[k + 2]);
        float b = fmaxf(eB[k], eB[k + 2]);
        float m = fmaxf(fmaxf(a, c), b);
        res[k] = m * pp[k] + rr[k];
      }
      *reinterpret_cast<float4*>(&dst[(i + 1) * ULW + cb]) =
          make_float4(res[0], res[1], res[2], res[3]);
    }
    __syncthreads();
    float* t_ = src;
    src = dst;
    dst = t_;
  }
  if (active && i >= 10 && i < 26 && (4 * j4 + 4) > 10 && (4 * j4) < 26) {
    float eA[6], eB[6], eC[6];
    row_win(src + i * ULW + cb, eA);
    row_win(src + (i + 1) * ULW + cb, eB);
    row_win(src + (i + 2) * ULW + cb, eC);
#pragma unroll
    for (int k = 0; k < 4; ++k) {
      int cj = 4 * j4 + k;
      if (cj >= 10 && cj < 26) {
        float a = fmaxf(fmaxf(eA[k], eA[k + 1]), eA[k + 2]);
        float c = fmaxf(fmaxf(eC[k], eC[k + 1]), eC[k + 2]);
        float b = fmaxf(eB[k], eB[k + 2]);
        float m = fmaxf(fmaxf(a, c), b);
        vout[(ti * VTILE + i - 10) * HW + tj * VTILE + cj - 10] = m;
      }
    }
  }
}

// ---------------------------------------------------------------------------
// K5: WpolV partials (32 MB, L3-resident). 512 blocks.
// ---------------------------------------------------------------------------
__global__ __launch_bounds__(256) void mv_polv(const float4* __restrict__ Wpol,
                                               const float4* __restrict__ v,
                                               float* __restrict__ partP) {
  int b = blockIdx.x;  // [0,512)
  int row = b / 16, cb = b - row * 16;
  int tid = threadIdx.x, wave = tid >> 6, lane = tid & 63;
  int ch = cb * 4 + wave;  // 0..63
  const float4* __restrict__ wp =
      Wpol + (size_t)row * NC4_POLROW + (size_t)ch * CH4 + lane;
  const float4* __restrict__ xp = v + (size_t)ch * CH4 + lane;
  float acc = span_dot(wp, xp);
  acc = wred(acc);
  if (lane == 0) partP[ch * 32 + row] = acc;
}

// ---------------------------------------------------------------------------
// K6: finish_pol (1 block).
// ---------------------------------------------------------------------------
__global__ __launch_bounds__(1024) void finish_pol(
    const float* __restrict__ partP, const float* __restrict__ bpol,
    const float* __restrict__ Whead, const float* __restrict__ bhead,
    const float* __restrict__ v, const int* __restrict__ pos,
    float* __restrict__ out) {
  __shared__ float red[32][32];
  __shared__ float hp[32];
  __shared__ float logits[8];
  int tid = threadIdx.x;
  int row = tid & 31, grp = tid >> 5;
  float s = 0.f;
  for (int b = grp; b < 256; b += 32) s += partP[b * 32 + row];
  red[grp][row] = s;
  __syncthreads();
  if (tid < 32) {
    float t = bpol[tid];
    for (int g = 0; g < 32; ++g) t += red[g][tid];
    hp[tid] = fmaxf(t, 0.f);
  }
  __syncthreads();
  if (tid < 8) {
    float t = bhead[tid];
    for (int k = 0; k < 32; ++k) t += Whead[tid * 32 + k] * hp[k];
    logits[tid] = t;
  }
  __syncthreads();
  if (tid == 0) {
    float mx = logits[0];
    for (int j = 1; j < 8; ++j) mx = fmaxf(mx, logits[j]);
    float e[8], sum = 0.f;
    for (int j = 0; j < 8; ++j) {
      e[j] = __expf(logits[j] - mx);
      sum += e[j];
    }
    for (int j = 0; j < 8; ++j) out[j] = e[j] / sum;
    out[8] = v[pos[0] * HW + pos[1]];
  }
}

extern "C" void kernel_launch(void* const* d_in, const int* in_sizes, int n_in,
                              void* d_out, int out_size, void* d_ws,
                              size_t ws_size, hipStream_t stream) {
  const float* x = (const float*)d_in[0];
  const int* pos = (const int*)d_in[1];
  const float* W1 = (const float*)d_in[2];
  const float* b1 = (const float*)d_in[3];
  const float* W2 = (const float*)d_in[4];
  const float* b2 = (const float*)d_in[5];
  const float* Wro = (const float*)d_in[6];
  const float* bro = (const float*)d_in[7];
  const float* Wri = (const float*)d_in[8];
  const float* bri = (const float*)d_in[9];
  const float* Wp = (const float*)d_in[10];
  const float* bp = (const float*)d_in[11];
  const float* Wpol = (const float*)d_in[12];
  const float* bpol = (const float*)d_in[13];
  const float* Whead = (const float*)d_in[14];
  const float* bhead = (const float*)d_in[15];
  float* ws = (float*)d_ws;
  float* out = (float*)d_out;

  float* part1 = ws + WS_PART1;
  float* partP = ws + WS_PARTP;
  float* h2 = ws + WS_H2;
  float* pbuf = ws + WS_P;
  float* rdbuf = ws + WS_RD;
  float* vbuf = ws + WS_V;

  // K1: W1@x partials
  mv_w1<<<1536, 256, 0, stream>>>((const float4*)W1, (const float4*)x, part1);
  // K2: h1 -> h2
  finish_h<<<1, 1024, 0, stream>>>(part1, b1, W2, b2, h2);
  // K3: rop (pipelined nt, sigmoids fused) + WpolX partials, interleaved
  ropx<<<2560, 256, 0, stream>>>((const float4*)Wro, (const float4*)Wri,
                                 (const float4*)Wp, h2, bro, bri, bp, pbuf,
                                 rdbuf, (const float4*)Wpol, (const float4*)x,
                                 partP);
  // K4: 10 value-iteration steps
  valiter_kernel<<<1024, 384, 0, stream>>>(pbuf, rdbuf, vbuf);
  // K5: WpolV partials
  mv_polv<<<512, 256, 0, stream>>>((const float4*)Wpol, (const float4*)vbuf,
                                   partP);
  // K6: heads + softmax + state value
  finish_pol<<<1, 1024, 0, stream>>>(partP, bpol, Whead, bhead, vbuf, pos,
                                     out);
}